// Round 1
// baseline (291.332 us; speedup 1.0000x reference)
//
#include <hip/hip_runtime.h>
#include <cfloat>

// Problem constants (fixed by reference): B=4, N=M=8192, D=3, fp32.
#define BB    4
#define NN    8192
#define MM    8192
#define NPTS  (BB * NN)      // 32768 points per tensor
#define CH    8              // j-chunks per direction
#define CHUNK (MM / CH)      // 1024 targets per chunk

// Monotone float->uint mapping so uint atomicMin == float min (handles negatives).
__device__ __forceinline__ unsigned int fmap(float f) {
    unsigned int u = __float_as_uint(f);
    return (u & 0x80000000u) ? ~u : (u | 0x80000000u);
}
__device__ __forceinline__ float funmap(unsigned int u) {
    u = (u & 0x80000000u) ? (u & 0x7FFFFFFFu) : ~u;
    return __uint_as_float(u);
}

// Pack (x,y,z,||p||^2), init min array to +max, zero output.
__global__ void chamfer_prep(const float* __restrict__ gts,
                             const float* __restrict__ preds,
                             float4* __restrict__ pg, float4* __restrict__ pp,
                             unsigned int* __restrict__ mins,
                             float* __restrict__ out, int out_size) {
    int idx = blockIdx.x * blockDim.x + threadIdx.x;   // 0 .. 2*NPTS-1
    const float* src = (idx < NPTS) ? gts : preds;
    int k = (idx < NPTS) ? idx : idx - NPTS;
    float x = src[k * 3 + 0], y = src[k * 3 + 1], z = src[k * 3 + 2];
    float4 v = make_float4(x, y, z, x * x + y * y + z * z);
    if (idx < NPTS) pg[k] = v; else pp[k] = v;
    mins[idx] = 0xFFFFFFFFu;
    if (idx < out_size) out[idx] = 0.f;
}

// Each thread: one query point, scans CHUNK targets (block-uniform index ->
// scalar loads). Tracks min_j(||t||^2 - 2*q.t); query's ||q||^2 added in reduce.
__global__ void __launch_bounds__(256, 8) chamfer_main(
        const float4* __restrict__ pg, const float4* __restrict__ pp,
        unsigned int* __restrict__ mins) {
    int bid  = blockIdx.x;
    int dir  = bid >> 10;           // 0: queries=gts targets=preds; 1: swapped
    int bi   = bid & 1023;
    int pblk = bi & 127;            // 128 point-blocks x 256 threads = 32768
    int ch   = bi >> 7;             // 8 chunks
    int qidx = pblk * 256 + threadIdx.x;   // global query point 0..32767
    int b    = qidx >> 13;                 // /8192 -> batch

    const float4* __restrict__ Q = dir ? pp : pg;
    const float4* __restrict__ T = dir ? pg : pp;
    float4 q = Q[qidx];
    const float4* __restrict__ t = T + b * MM + ch * CHUNK;

    float m0 = FLT_MAX, m1 = FLT_MAX, m2 = FLT_MAX, m3 = FLT_MAX;
    #pragma unroll 4
    for (int j = 0; j < CHUNK; j += 4) {
        float4 t0 = t[j + 0];
        float4 t1 = t[j + 1];
        float4 t2 = t[j + 2];
        float4 t3 = t[j + 3];
        float d0 = q.x * t0.x + q.y * t0.y + q.z * t0.z;
        float d1 = q.x * t1.x + q.y * t1.y + q.z * t1.z;
        float d2 = q.x * t2.x + q.y * t2.y + q.z * t2.z;
        float d3 = q.x * t3.x + q.y * t3.y + q.z * t3.z;
        m0 = fminf(m0, fmaf(-2.f, d0, t0.w));
        m1 = fminf(m1, fmaf(-2.f, d1, t1.w));
        m2 = fminf(m2, fmaf(-2.f, d2, t2.w));
        m3 = fminf(m3, fmaf(-2.f, d3, t3.w));
    }
    float m = fminf(fminf(m0, m1), fminf(m2, m3));
    atomicMin(&mins[dir * NPTS + qidx], fmap(m));
}

// Sum over all points: unmap(min) + ||q||^2 ; block reduce; one atomicAdd/block.
__global__ void chamfer_reduce(const unsigned int* __restrict__ mins,
                               const float4* __restrict__ pg,
                               const float4* __restrict__ pp,
                               float* __restrict__ out) {
    int g = blockIdx.x * blockDim.x + threadIdx.x;   // 0 .. 2*NPTS-1
    float f  = funmap(mins[g]);
    float xx = (g < NPTS) ? pg[g].w : pp[g - NPTS].w;
    float val = f + xx;

    #pragma unroll
    for (int off = 32; off > 0; off >>= 1)
        val += __shfl_down(val, off, 64);

    __shared__ float s[4];
    int lane = threadIdx.x & 63;
    int w    = threadIdx.x >> 6;
    if (lane == 0) s[w] = val;
    __syncthreads();
    if (threadIdx.x == 0)
        atomicAdd(out, s[0] + s[1] + s[2] + s[3]);
}

extern "C" void kernel_launch(void* const* d_in, const int* in_sizes, int n_in,
                              void* d_out, int out_size, void* d_ws, size_t ws_size,
                              hipStream_t stream) {
    const float* gts   = (const float*)d_in[0];
    const float* preds = (const float*)d_in[1];
    float* out = (float*)d_out;

    char* ws = (char*)d_ws;
    float4* pg = (float4*)ws;                                   // 512 KB
    float4* pp = (float4*)(ws + (size_t)NPTS * 16);             // 512 KB
    unsigned int* mins = (unsigned int*)(ws + (size_t)2 * NPTS * 16); // 256 KB

    chamfer_prep  <<<(2 * NPTS) / 256, 256, 0, stream>>>(gts, preds, pg, pp, mins, out, out_size);
    chamfer_main  <<<2 * CH * (NPTS / 256), 256, 0, stream>>>(pg, pp, mins);
    chamfer_reduce<<<(2 * NPTS) / 256, 256, 0, stream>>>(mins, pg, pp, out);
}

// Round 2
// 98.975 us; speedup vs baseline: 2.9435x; 2.9435x over previous
//
#include <hip/hip_runtime.h>
#include <cfloat>

// Problem constants (fixed by reference): B=4, N=M=8192, D=3, fp32.
#define BB    4
#define NN    8192
#define MM    8192
#define NPTS  (BB * NN)      // 32768 points per tensor
#define CH    32             // target chunks per direction
#define CHUNK (MM / CH)      // 256 targets per chunk (4 KB LDS)
#define QT    4              // queries per thread (register tile)
#define QB    (256 * QT)     // 1024 queries per block
#define QBLKS (NPTS / QB)    // 32 query-blocks per direction

// Monotone float->uint mapping so uint atomicMin == float min (handles negatives).
__device__ __forceinline__ unsigned int fmap(float f) {
    unsigned int u = __float_as_uint(f);
    return (u & 0x80000000u) ? ~u : (u | 0x80000000u);
}
__device__ __forceinline__ float funmap(unsigned int u) {
    u = (u & 0x80000000u) ? (u & 0x7FFFFFFFu) : ~u;
    return __uint_as_float(u);
}

// Pack (x,y,z, ||p||^2 / 2), init min array to +max (ordered uint), zero out.
__global__ void chamfer_prep(const float* __restrict__ gts,
                             const float* __restrict__ preds,
                             float4* __restrict__ pg, float4* __restrict__ pp,
                             unsigned int* __restrict__ mins,
                             float* __restrict__ out, int out_size) {
    int idx = blockIdx.x * blockDim.x + threadIdx.x;   // 0 .. 2*NPTS-1
    const float* src = (idx < NPTS) ? gts : preds;
    int k = (idx < NPTS) ? idx : idx - NPTS;
    float x = src[k * 3 + 0], y = src[k * 3 + 1], z = src[k * 3 + 2];
    float4 v = make_float4(x, y, z, 0.5f * (x * x + y * y + z * z));
    if (idx < NPTS) pg[k] = v; else pp[k] = v;
    mins[idx] = 0xFFFFFFFFu;
    if (idx < out_size) out[idx] = 0.f;
}

// Each thread: QT=4 query points vs a CHUNK of targets staged in LDS.
// Tracks min_j( ||t||^2/2 - q.t ); final value = 2*(min + ||q||^2/2) in reduce.
// Inner op count: 3 fma + 1 min per pair = 4 VALU ops (neg via VOP3 modifiers).
__global__ void __launch_bounds__(256, 8) chamfer_main(
        const float4* __restrict__ pg, const float4* __restrict__ pp,
        unsigned int* __restrict__ mins) {
    __shared__ float4 st[CHUNK];

    int bid  = blockIdx.x;          // grid = 2 * QBLKS * CH = 2048
    int dir  = bid >> 10;           // 1024 blocks per direction
    int bi   = bid & 1023;
    int pblk = bi & (QBLKS - 1);    // 32 query-blocks
    int ch   = bi >> 5;             // 32 chunks
    int b    = pblk >> 3;           // 8 query-blocks per batch (uniform per block)

    const float4* __restrict__ Q = dir ? pp : pg;
    const float4* __restrict__ T = dir ? pg : pp;
    const float4* __restrict__ t = T + b * MM + ch * CHUNK;

    // Stage chunk: 256 threads x one float4 each, coalesced.
    st[threadIdx.x] = t[threadIdx.x];

    int qbase = pblk * QB + threadIdx.x;
    float qx[QT], qy[QT], qz[QT], m[QT];
    #pragma unroll
    for (int k = 0; k < QT; ++k) {
        float4 q = Q[qbase + 256 * k];
        qx[k] = q.x; qy[k] = q.y; qz[k] = q.z;
        m[k] = FLT_MAX;
    }
    __syncthreads();

    #pragma unroll 4
    for (int j = 0; j < CHUNK; ++j) {
        float4 tj = st[j];          // broadcast ds_read_b128, conflict-free
        #pragma unroll
        for (int k = 0; k < QT; ++k) {
            float s = fmaf(-qx[k], tj.x,
                      fmaf(-qy[k], tj.y,
                      fmaf(-qz[k], tj.z, tj.w)));
            m[k] = fminf(m[k], s);
        }
    }

    #pragma unroll
    for (int k = 0; k < QT; ++k)
        atomicMin(&mins[dir * NPTS + qbase + 256 * k], fmap(m[k]));
}

// Sum over all points: 2*(unmap(min) + ||q||^2/2); block reduce; one atomicAdd.
__global__ void chamfer_reduce(const unsigned int* __restrict__ mins,
                               const float4* __restrict__ pg,
                               const float4* __restrict__ pp,
                               float* __restrict__ out) {
    int g = blockIdx.x * blockDim.x + threadIdx.x;   // 0 .. 2*NPTS-1
    float f = funmap(mins[g]);
    float w = (g < NPTS) ? pg[g].w : pp[g - NPTS].w;
    float val = 2.0f * (f + w);

    #pragma unroll
    for (int off = 32; off > 0; off >>= 1)
        val += __shfl_down(val, off, 64);

    __shared__ float s[4];
    int lane = threadIdx.x & 63;
    int w_id = threadIdx.x >> 6;
    if (lane == 0) s[w_id] = val;
    __syncthreads();
    if (threadIdx.x == 0)
        atomicAdd(out, s[0] + s[1] + s[2] + s[3]);
}

extern "C" void kernel_launch(void* const* d_in, const int* in_sizes, int n_in,
                              void* d_out, int out_size, void* d_ws, size_t ws_size,
                              hipStream_t stream) {
    const float* gts   = (const float*)d_in[0];
    const float* preds = (const float*)d_in[1];
    float* out = (float*)d_out;

    char* ws = (char*)d_ws;
    float4* pg = (float4*)ws;                                         // 512 KB
    float4* pp = (float4*)(ws + (size_t)NPTS * 16);                   // 512 KB
    unsigned int* mins = (unsigned int*)(ws + (size_t)2 * NPTS * 16); // 256 KB

    chamfer_prep  <<<(2 * NPTS) / 256, 256, 0, stream>>>(gts, preds, pg, pp, mins, out, out_size);
    chamfer_main  <<<2 * QBLKS * CH, 256, 0, stream>>>(pg, pp, mins);
    chamfer_reduce<<<(2 * NPTS) / 256, 256, 0, stream>>>(mins, pg, pp, out);
}